// Round 1
// baseline (735.518 us; speedup 1.0000x reference)
//
#include <hip/hip_runtime.h>
#include <cstddef>

#define BB 4096
#define DIN 2048
#define RR 7
#define DP 128
#define KK 25
#define DC 16
#define NITERS 3
#define RKH (RR*KK*DC)   // 2800
#define RK  (RR*KK)      // 175
#define KH  (KK*DC)      // 400
#define HD  (RR*DC)      // 112
#define H4  (4*HD)       // 448

// ---------------------------------------------------------------------------
// Kernel 1: act = clip(sigmoid(LN(z) @ W_act + b_act))  — one block per row b
// ---------------------------------------------------------------------------
__global__ __launch_bounds__(256) void act_kernel(
    const float* __restrict__ z, const float* __restrict__ g, const float* __restrict__ bb,
    const float* __restrict__ Wa, const float* __restrict__ ba,
    float* __restrict__ act_out)
{
    int b = blockIdx.x;
    int t = threadIdx.x;
    __shared__ float zs[DIN];
    __shared__ float ws1[4], ws2[4];
    __shared__ float wr[4][RR];
    const float* zr = z + (size_t)b * DIN;
    float s = 0.f, s2 = 0.f;
    for (int i = t; i < DIN; i += 256) {
        float v = zr[i]; zs[i] = v; s += v; s2 += v * v;
    }
    for (int off = 32; off; off >>= 1) { s += __shfl_down(s, off); s2 += __shfl_down(s2, off); }
    int w = t >> 6, lane = t & 63;
    if (lane == 0) { ws1[w] = s; ws2[w] = s2; }
    __syncthreads();
    s  = ws1[0] + ws1[1] + ws1[2] + ws1[3];
    s2 = ws2[0] + ws2[1] + ws2[2] + ws2[3];
    float mean = s * (1.0f / DIN);
    float var  = s2 * (1.0f / DIN) - mean * mean;
    float rstd = rsqrtf(var + 1e-5f);
    float acc[RR];
#pragma unroll
    for (int r = 0; r < RR; ++r) acc[r] = 0.f;
    for (int i = t; i < DIN; i += 256) {
        float y = (zs[i] - mean) * rstd * g[i] + bb[i];
#pragma unroll
        for (int r = 0; r < RR; ++r) acc[r] += y * Wa[i * RR + r];
    }
    for (int off = 32; off; off >>= 1) {
#pragma unroll
        for (int r = 0; r < RR; ++r) acc[r] += __shfl_down(acc[r], off);
    }
    if (lane == 0) {
#pragma unroll
        for (int r = 0; r < RR; ++r) wr[w][r] = acc[r];
    }
    __syncthreads();
    if (t < RR) {
        float v = wr[0][t] + wr[1][t] + wr[2][t] + wr[3][t] + ba[t];
        float sg = 1.0f / (1.0f + expf(-v));
        sg = fminf(fmaxf(sg, 0.0f), 1.0f);
        act_out[(size_t)b * RR + t] = sg;
    }
}

// ---------------------------------------------------------------------------
// Kernel 2: pose = squash((z @ W_prim + b_prim).reshape(B,R,DP))
// Tile 64 rows x 128 cols (one full r per block) so squash is block-local.
// ---------------------------------------------------------------------------
__global__ __launch_bounds__(256) void pose_kernel(
    const float* __restrict__ z, const float* __restrict__ Wp, const float* __restrict__ bp,
    float* __restrict__ pose_out)
{
    __shared__ __align__(16) float As[64 * 36];   // 64 rows, stride 36 (pad)
    __shared__ __align__(16) float Bs[32 * 128];  // BK=32 x 128 cols
    int m0 = blockIdx.x * 64;
    int r  = blockIdx.y;
    int n0 = r * DP;
    int t  = threadIdx.x;
    int rg = t >> 5;   // 0..7  -> rows rg*8..+7
    int cg = t & 31;   // cols cg*4..+3
    float acc[8][4] = {};
    for (int kt = 0; kt < DIN; kt += 32) {
#pragma unroll
        for (int q = 0; q < 2; ++q) {
            int s = t * 2 + q;                 // 0..511
            int row = s >> 3, k4 = s & 7;
            float4 v = *(const float4*)(z + (size_t)(m0 + row) * DIN + kt + k4 * 4);
            *(float4*)(As + row * 36 + k4 * 4) = v;
        }
#pragma unroll
        for (int q = 0; q < 4; ++q) {
            int s = t + 256 * q;               // 0..1023
            int row = s >> 5, c4 = s & 31;
            float4 v = *(const float4*)(Wp + (size_t)(kt + row) * (RR * DP) + n0 + c4 * 4);
            *(float4*)(Bs + row * 128 + c4 * 4) = v;
        }
        __syncthreads();
#pragma unroll
        for (int kk = 0; kk < 32; ++kk) {
            float4 bv = *(const float4*)(Bs + kk * 128 + cg * 4);
#pragma unroll
            for (int j = 0; j < 8; ++j) {
                float a = As[(rg * 8 + j) * 36 + kk];
                acc[j][0] += a * bv.x; acc[j][1] += a * bv.y;
                acc[j][2] += a * bv.z; acc[j][3] += a * bv.w;
            }
        }
        __syncthreads();
    }
    float bi0 = bp[n0 + cg * 4], bi1 = bp[n0 + cg * 4 + 1];
    float bi2 = bp[n0 + cg * 4 + 2], bi3 = bp[n0 + cg * 4 + 3];
#pragma unroll
    for (int j = 0; j < 8; ++j) {
        float x0 = acc[j][0] + bi0, x1 = acc[j][1] + bi1;
        float x2 = acc[j][2] + bi2, x3 = acc[j][3] + bi3;
        float ns = x0 * x0 + x1 * x1 + x2 * x2 + x3 * x3;
        for (int off = 1; off < 32; off <<= 1) ns += __shfl_xor(ns, off);
        float factor = (ns / fmaxf(1.0f + ns, 1e-6f)) / (sqrtf(ns) + 1e-6f);
        int row = m0 + rg * 8 + j;
        float4 o = make_float4(x0 * factor, x1 * factor, x2 * factor, x3 * factor);
        *(float4*)(pose_out + ((size_t)row * RR + r) * DP + cg * 4) = o;
    }
}

// ---------------------------------------------------------------------------
// Kernel 3: votes u[b,r,k,h] = sum_d pose[b,r,d]*w_caps[r,d,k,h]
// Per-r GEMM [64 x 128] @ [128 x 80-col-chunk]. Writes u into route_class_emb
// output region (same shape) — routing kernel consumes & overwrites it.
// ---------------------------------------------------------------------------
__global__ __launch_bounds__(256) void votes_kernel(
    const float* __restrict__ pose, const float* __restrict__ wc,
    float* __restrict__ u_out)
{
    __shared__ float As[64 * 129];                 // pose tile, pad 129
    __shared__ __align__(16) float Bs[64 * 80];    // half-depth w_caps chunk
    int m0 = blockIdx.x * 64;
    int r  = blockIdx.y;
    int n0 = blockIdx.z * 80;
    int t  = threadIdx.x;
    const size_t wbase = (size_t)r * DP * KH;
#pragma unroll
    for (int q = 0; q < 8; ++q) {
        int s = t + 256 * q;                       // 0..2047 float4 slots
        int row = s >> 5, d4 = s & 31;
        float4 v = *(const float4*)(pose + ((size_t)(m0 + row) * RR + r) * DP + d4 * 4);
        As[row * 129 + d4 * 4 + 0] = v.x;
        As[row * 129 + d4 * 4 + 1] = v.y;
        As[row * 129 + d4 * 4 + 2] = v.z;
        As[row * 129 + d4 * 4 + 3] = v.w;
    }
    int m4 = t >> 4, n5 = t & 15;
    float acc[4][5];
#pragma unroll
    for (int i = 0; i < 4; ++i)
#pragma unroll
        for (int j = 0; j < 5; ++j) acc[i][j] = 0.f;
    for (int kt = 0; kt < DP; kt += 64) {
        __syncthreads();
#pragma unroll
        for (int q = 0; q < 5; ++q) {
            int s = t + 256 * q;                   // 0..1279
            int d = s / 20, c4 = s % 20;
            float4 v = *(const float4*)(wc + wbase + (size_t)(kt + d) * KH + n0 + c4 * 4);
            *(float4*)(Bs + d * 80 + c4 * 4) = v;
        }
        __syncthreads();
#pragma unroll 4
        for (int dd = 0; dd < 64; ++dd) {
            int d = kt + dd;
            float b_[5];
#pragma unroll
            for (int j = 0; j < 5; ++j) b_[j] = Bs[dd * 80 + n5 * 5 + j];
#pragma unroll
            for (int i = 0; i < 4; ++i) {
                float a = As[(m4 * 4 + i) * 129 + d];
#pragma unroll
                for (int j = 0; j < 5; ++j) acc[i][j] += a * b_[j];
            }
        }
    }
#pragma unroll
    for (int i = 0; i < 4; ++i) {
        int row = m0 + m4 * 4 + i;
        size_t base = ((size_t)row * RR + r) * KH + n0 + n5 * 5;
#pragma unroll
        for (int j = 0; j < 5; ++j) u_out[base + j] = acc[i][j];
    }
}

// ---------------------------------------------------------------------------
// Kernel 4: routing — one wave (64 threads) per batch row b. u[b] in LDS.
// ---------------------------------------------------------------------------
__global__ __launch_bounds__(64) void routing_kernel(
    const float* __restrict__ u_in, const float* __restrict__ act_in,
    const float* __restrict__ lncg, const float* __restrict__ lncb,
    const float* __restrict__ beta_u,
    float* __restrict__ q_out, float* __restrict__ cp_out,
    float* __restrict__ ca_out, float* __restrict__ rce_out,
    float* __restrict__ ce_out)
{
    __shared__ __align__(16) float U[RKH];
    __shared__ float Q[RK];
    __shared__ float CP[KH];
    __shared__ float AG[RK];
    __shared__ float A7[RR];
    int b = blockIdx.x, t = threadIdx.x;
    const float4* u4 = (const float4*)(u_in + (size_t)b * RKH);
    float4* U4 = (float4*)U;
    for (int p = t; p < RKH / 4; p += 64) U4[p] = u4[p];
    if (t < RR) A7[t] = act_in[(size_t)b * RR + t];
    for (int p = t; p < RK; p += 64) Q[p] = 1.0f / KK;
    __syncthreads();
    for (int it = 0; it < NITERS; ++it) {
        for (int p = t; p < KH; p += 64) {
            int k = p / DC;
            float s = 0.f;
#pragma unroll
            for (int r = 0; r < RR; ++r) s += Q[r * KK + k] * A7[r] * U[r * KH + p];
            CP[p] = s;
        }
        __syncthreads();
        if (t < KK) {
            float m = 0.f;
#pragma unroll
            for (int h = 0; h < DC; ++h) m += CP[t * DC + h];
            m *= (1.0f / DC);
            float v = 0.f;
#pragma unroll
            for (int h = 0; h < DC; ++h) { float d = CP[t * DC + h] - m; v += d * d; }
            v *= (1.0f / DC);
            float rstd = rsqrtf(v + 1e-5f);
#pragma unroll
            for (int h = 0; h < DC; ++h)
                CP[t * DC + h] = (CP[t * DC + h] - m) * rstd * lncg[h] + lncb[h];
        }
        __syncthreads();
        for (int p = t; p < RK; p += 64) {
            int r = p / KK, k = p % KK;
            float s = 0.f;
#pragma unroll
            for (int h = 0; h < DC; ++h) s += CP[k * DC + h] * U[r * KH + k * DC + h];
            AG[p] = s * 0.25f;   // 1/sqrt(16)
        }
        __syncthreads();
        if (t < RR) {
            float mx = -1e30f;
            for (int k = 0; k < KK; ++k) mx = fmaxf(mx, AG[t * KK + k]);
            float e[KK], sum = 0.f;
            for (int k = 0; k < KK; ++k) { e[k] = expf(AG[t * KK + k] - mx); sum += e[k]; }
            float inv = 1.0f / sum;
            for (int k = 0; k < KK; ++k) Q[t * KK + k] = e[k] * inv;
        }
        __syncthreads();
    }
    if (t < KK) {
        float s = 0.f;
#pragma unroll
        for (int r = 0; r < RR; ++r) s += Q[r * KK + t] * A7[r];
        ca_out[(size_t)b * KK + t] = 1.0f / (1.0f + expf(-(beta_u[t] + s)));
    }
    for (int p = t; p < RK; p += 64) q_out[(size_t)b * RK + p] = Q[p];
    for (int p = t; p < KH; p += 64) cp_out[(size_t)b * KH + p] = CP[p];
    float4* rce4 = (float4*)(rce_out + (size_t)b * RKH);
    float4* ce4  = (float4*)ce_out;
    for (int p4 = t; p4 < RKH / 4; p4 += 64) {
        int base = p4 * 4;
        int r  = base / KH;
        int k  = (base % KH) / DC;
        int h0 = base % DC;
        float qv = Q[r * KK + k];
        float4 uv = U4[p4];
        float4 rv = make_float4(qv * uv.x, qv * uv.y, qv * uv.z, qv * uv.w);
        rce4[p4] = rv;
        size_t ci = ((size_t)b * RKH + (size_t)k * HD + (size_t)r * DC + h0) >> 2;
        ce4[ci] = rv;
    }
}

// ---------------------------------------------------------------------------
// Kernel 5: head — LN(class_embed) @ W_h1 -> gelu -> dot W_h2 (h never stored)
// 64 rows per block; W_h1 streamed through LDS in 64-col chunks.
// ---------------------------------------------------------------------------
__global__ __launch_bounds__(256) void head_kernel(
    const float* __restrict__ ce, const float* __restrict__ g, const float* __restrict__ bb,
    const float* __restrict__ W1, const float* __restrict__ b1,
    const float* __restrict__ W2, const float* __restrict__ b2,
    float* __restrict__ logits)
{
    __shared__ __align__(16) float Y[64 * HD];   // LN'ed rows
    __shared__ float Wc[HD * 64];                // [i][col]
    __shared__ float Lg[64];
    int row0 = blockIdx.x * 64;
    int t = threadIdx.x;
    for (int s = t; s < 64 * HD; s += 256) Y[s] = ce[(size_t)row0 * HD + s];
    __syncthreads();
    if (t < 64) {
        float m = 0.f;
        for (int i = 0; i < HD; ++i) m += Y[t * HD + i];
        m *= (1.0f / HD);
        float v = 0.f;
        for (int i = 0; i < HD; ++i) { float d = Y[t * HD + i] - m; v += d * d; }
        v *= (1.0f / HD);
        float rstd = rsqrtf(v + 1e-5f);
        for (int i = 0; i < HD; ++i) Y[t * HD + i] = (Y[t * HD + i] - m) * rstd * g[i] + bb[i];
    }
    int rg = t >> 4;   // 0..15 -> rows rg*4..+3
    int cg = t & 15;   // cols cg*4..+3 within 64-col chunk
    float accRow[4] = {0.f, 0.f, 0.f, 0.f};
    for (int c0 = 0; c0 < H4; c0 += 64) {
        __syncthreads();
        for (int s = t; s < HD * 64; s += 256) {
            int i = s >> 6, c = s & 63;
            Wc[i * 64 + c] = W1[(size_t)i * H4 + c0 + c];
        }
        __syncthreads();
        float b1v[4], w2v[4];
#pragma unroll
        for (int c = 0; c < 4; ++c) { b1v[c] = b1[c0 + cg * 4 + c]; w2v[c] = W2[c0 + cg * 4 + c]; }
        float s_[4][4];
#pragma unroll
        for (int rr = 0; rr < 4; ++rr)
#pragma unroll
            for (int c = 0; c < 4; ++c) s_[rr][c] = b1v[c];
        for (int i4 = 0; i4 < HD / 4; ++i4) {
            float4 y4[4];
#pragma unroll
            for (int rr = 0; rr < 4; ++rr)
                y4[rr] = *(const float4*)(Y + (rg * 4 + rr) * HD + i4 * 4);
#pragma unroll
            for (int is = 0; is < 4; ++is) {
                float w_[4];
#pragma unroll
                for (int c = 0; c < 4; ++c) w_[c] = Wc[(i4 * 4 + is) * 64 + cg * 4 + c];
#pragma unroll
                for (int rr = 0; rr < 4; ++rr) {
                    float yv = (is == 0) ? y4[rr].x : (is == 1) ? y4[rr].y : (is == 2) ? y4[rr].z : y4[rr].w;
#pragma unroll
                    for (int c = 0; c < 4; ++c) s_[rr][c] += yv * w_[c];
                }
            }
        }
#pragma unroll
        for (int rr = 0; rr < 4; ++rr) {
#pragma unroll
            for (int c = 0; c < 4; ++c) {
                float x = s_[rr][c];
                float ge = 0.5f * x * (1.0f + erff(x * 0.70710678118654752440f));
                accRow[rr] += ge * w2v[c];
            }
        }
    }
#pragma unroll
    for (int rr = 0; rr < 4; ++rr) {
        float v = accRow[rr];
        v += __shfl_xor(v, 1); v += __shfl_xor(v, 2);
        v += __shfl_xor(v, 4); v += __shfl_xor(v, 8);
        if (cg == 0) Lg[rg * 4 + rr] = v;
    }
    __syncthreads();
    if (t < 64) logits[row0 + t] = Lg[t] + b2[0];
}

// ---------------------------------------------------------------------------
extern "C" void kernel_launch(void* const* d_in, const int* in_sizes, int n_in,
                              void* d_out, int out_size, void* d_ws, size_t ws_size,
                              hipStream_t stream) {
    const float* z    = (const float*)d_in[0];
    const float* Wp   = (const float*)d_in[1];
    const float* bp   = (const float*)d_in[2];
    const float* lnag = (const float*)d_in[3];
    const float* lnab = (const float*)d_in[4];
    const float* Wa   = (const float*)d_in[5];
    const float* ba   = (const float*)d_in[6];
    const float* wc   = (const float*)d_in[7];
    const float* lncg = (const float*)d_in[8];
    const float* lncb = (const float*)d_in[9];
    const float* beta = (const float*)d_in[10];
    const float* lnhg = (const float*)d_in[11];
    const float* lnhb = (const float*)d_in[12];
    const float* W1   = (const float*)d_in[13];
    const float* b1   = (const float*)d_in[14];
    const float* W2   = (const float*)d_in[15];
    const float* b2   = (const float*)d_in[16];

    float* out = (float*)d_out;
    float* o_logits = out;                                   // [B,K]
    float* o_ce   = o_logits + (size_t)BB * KK;              // [B,K,112]
    float* o_cp   = o_ce   + (size_t)BB * KK * HD;           // [B,K,16]
    float* o_ca   = o_cp   + (size_t)BB * KK * DC;           // [B,K]
    float* o_q    = o_ca   + (size_t)BB * KK;                // [B,R,K]
    float* o_pose = o_q    + (size_t)BB * RK;                // [B,R,128]
    float* o_act  = o_pose + (size_t)BB * RR * DP;           // [B,R]
    float* o_rce  = o_act  + (size_t)BB * RR;                // [B,R,K,16]

    hipLaunchKernelGGL(act_kernel, dim3(BB), dim3(256), 0, stream,
                       z, lnag, lnab, Wa, ba, o_act);
    hipLaunchKernelGGL(pose_kernel, dim3(BB / 64, RR), dim3(256), 0, stream,
                       z, Wp, bp, o_pose);
    hipLaunchKernelGGL(votes_kernel, dim3(BB / 64, RR, 5), dim3(256), 0, stream,
                       o_pose, wc, o_rce);
    hipLaunchKernelGGL(routing_kernel, dim3(BB), dim3(64), 0, stream,
                       o_rce, o_act, lncg, lncb, beta, o_q, o_cp, o_ca, o_rce, o_ce);
    hipLaunchKernelGGL(head_kernel, dim3(BB * KK / 64), dim3(256), 0, stream,
                       o_ce, lnhg, lnhb, W1, b1, W2, b2, o_logits);
}

// Round 2
// 384.028 us; speedup vs baseline: 1.9153x; 1.9153x over previous
//
#include <hip/hip_runtime.h>
#include <cstddef>

#define BB 4096
#define DIN 2048
#define RR 7
#define DP 128
#define KK 25
#define DC 16
#define NITERS 3
#define RKH (RR*KK*DC)   // 2800
#define RK  (RR*KK)      // 175
#define KH  (KK*DC)      // 400
#define HD  (RR*DC)      // 112
#define H4  (4*HD)       // 448

typedef __attribute__((ext_vector_type(8))) short bf16x8;
typedef __attribute__((ext_vector_type(4))) float f32x4;

__device__ __forceinline__ unsigned pk_bf16(float a, float b) {
    union { float f; unsigned u; } xa, xb;
    xa.f = a; xb.f = b;
    unsigned ua = (xa.u + 0x7FFFu + ((xa.u >> 16) & 1u)) >> 16;
    unsigned ub = (xb.u + 0x7FFFu + ((xb.u >> 16) & 1u)) >> 16;
    return (ua & 0xFFFFu) | (ub << 16);
}

__device__ __forceinline__ float gelu_tanh(float x) {
    float x3 = x * x * x;
    float tt = 0.7978845608f * (x + 0.044715f * x3);
    float e = __expf(2.0f * tt);
    float th = 1.0f - 2.0f / (e + 1.0f);
    return 0.5f * x * (1.0f + th);
}

// ---------------------------------------------------------------------------
// Prep: transpose fp32 [RS][CS] -> bf16 [CS][RS].  grid (ceil(RS/64), ceil(CS/64), batch)
// Requires RS % 4 == 0, CS % 4 == 0.
// ---------------------------------------------------------------------------
__global__ __launch_bounds__(256) void transpose_cvt_kernel(
    const float* __restrict__ src, unsigned short* __restrict__ dst, int RS, int CS)
{
    __shared__ float T[64][65];
    int r0 = blockIdx.x * 64, c0 = blockIdx.y * 64;
    size_t bo = (size_t)blockIdx.z * RS * CS;
    src += bo; dst += bo;
    int t = threadIdx.x;
    for (int s = t; s < 64 * 16; s += 256) {
        int row = s >> 4, c4 = s & 15;
        int gr = r0 + row, gc = c0 + c4 * 4;
        float4 v = make_float4(0.f, 0.f, 0.f, 0.f);
        if (gr < RS && gc < CS) v = *(const float4*)(src + (size_t)gr * CS + gc);
        T[row][c4 * 4 + 0] = v.x; T[row][c4 * 4 + 1] = v.y;
        T[row][c4 * 4 + 2] = v.z; T[row][c4 * 4 + 3] = v.w;
    }
    __syncthreads();
    for (int s = t; s < 64 * 16; s += 256) {
        int col = s >> 4, r4 = s & 15;
        int gc = c0 + col, gr = r0 + r4 * 4;
        if (gc < CS && gr + 3 < RS) {
            unsigned lo = pk_bf16(T[r4 * 4 + 0][col], T[r4 * 4 + 1][col]);
            unsigned hi = pk_bf16(T[r4 * 4 + 2][col], T[r4 * 4 + 3][col]);
            *(uint2*)(dst + (size_t)gc * RS + gr) = make_uint2(lo, hi);
        }
    }
}

// ---------------------------------------------------------------------------
// Kernel 1: act = clip(sigmoid(LN(z) @ W_act + b_act))  — one block per row b
// ---------------------------------------------------------------------------
__global__ __launch_bounds__(256) void act_kernel(
    const float* __restrict__ z, const float* __restrict__ g, const float* __restrict__ bb,
    const float* __restrict__ Wa, const float* __restrict__ ba,
    float* __restrict__ act_out)
{
    int b = blockIdx.x;
    int t = threadIdx.x;
    __shared__ float zs[DIN];
    __shared__ float ws1[4], ws2[4];
    __shared__ float wr[4][RR];
    const float* zr = z + (size_t)b * DIN;
    float s = 0.f, s2 = 0.f;
    for (int i = t; i < DIN; i += 256) {
        float v = zr[i]; zs[i] = v; s += v; s2 += v * v;
    }
    for (int off = 32; off; off >>= 1) { s += __shfl_down(s, off); s2 += __shfl_down(s2, off); }
    int w = t >> 6, lane = t & 63;
    if (lane == 0) { ws1[w] = s; ws2[w] = s2; }
    __syncthreads();
    s  = ws1[0] + ws1[1] + ws1[2] + ws1[3];
    s2 = ws2[0] + ws2[1] + ws2[2] + ws2[3];
    float mean = s * (1.0f / DIN);
    float var  = s2 * (1.0f / DIN) - mean * mean;
    float rstd = rsqrtf(var + 1e-5f);
    float acc[RR];
#pragma unroll
    for (int r = 0; r < RR; ++r) acc[r] = 0.f;
    for (int i = t; i < DIN; i += 256) {
        float y = (zs[i] - mean) * rstd * g[i] + bb[i];
#pragma unroll
        for (int r = 0; r < RR; ++r) acc[r] += y * Wa[i * RR + r];
    }
    for (int off = 32; off; off >>= 1) {
#pragma unroll
        for (int r = 0; r < RR; ++r) acc[r] += __shfl_down(acc[r], off);
    }
    if (lane == 0) {
#pragma unroll
        for (int r = 0; r < RR; ++r) wr[w][r] = acc[r];
    }
    __syncthreads();
    if (t < RR) {
        float v = wr[0][t] + wr[1][t] + wr[2][t] + wr[3][t] + ba[t];
        float sg = 1.0f / (1.0f + expf(-v));
        sg = fminf(fmaxf(sg, 0.0f), 1.0f);
        act_out[(size_t)b * RR + t] = sg;
    }
}

// ---------------------------------------------------------------------------
// Kernel 2 (MFMA): pose = squash(z @ W_prim + b_prim)
// Tile 128x128 (one r per block column). A: z fp32->bf16 in staging; B: WpT bf16 (ws).
// ---------------------------------------------------------------------------
__global__ __launch_bounds__(256) void pose_mfma(
    const float* __restrict__ z, const unsigned short* __restrict__ WpT,
    const float* __restrict__ bp, float* __restrict__ pose_out)
{
    __shared__ __align__(16) unsigned short As[128 * 40];  // [row][k] stride 40
    __shared__ __align__(16) unsigned short Bs[128 * 40];  // [col][k] stride 40
    __shared__ float sq[2][128];
    int m0 = blockIdx.x * 128, r = blockIdx.y, t = threadIdx.x;
    int n0 = r * DP;
    int w = t >> 6, l = t & 63;
    int lrow = l & 15, koff = l >> 4;
    int rbase = (w >> 1) * 64, cbase = (w & 1) * 64;
    f32x4 acc[4][4];
#pragma unroll
    for (int i = 0; i < 4; ++i)
#pragma unroll
        for (int j = 0; j < 4; ++j) acc[i][j] = 0.0f;
    for (int kt = 0; kt < DIN; kt += 32) {
        // stage A: z fp32 -> bf16
#pragma unroll
        for (int q = 0; q < 4; ++q) {
            int s = t + 256 * q;
            int row = s >> 3, k4 = s & 7;
            float4 v = *(const float4*)(z + (size_t)(m0 + row) * DIN + kt + k4 * 4);
            *(uint2*)(As + row * 40 + k4 * 4) = make_uint2(pk_bf16(v.x, v.y), pk_bf16(v.z, v.w));
        }
        // stage B: WpT bf16 direct
#pragma unroll
        for (int q = 0; q < 2; ++q) {
            int s = t + 256 * q;
            int col = s >> 2, k8 = s & 3;
            uint4 v = *(const uint4*)(WpT + (size_t)(n0 + col) * DIN + kt + k8 * 8);
            *(uint4*)(Bs + col * 40 + k8 * 8) = v;
        }
        __syncthreads();
        bf16x8 a[4], b[4];
#pragma unroll
        for (int i = 0; i < 4; ++i)
            a[i] = *(const bf16x8*)(As + (rbase + i * 16 + lrow) * 40 + koff * 8);
#pragma unroll
        for (int j = 0; j < 4; ++j)
            b[j] = *(const bf16x8*)(Bs + (cbase + j * 16 + lrow) * 40 + koff * 8);
#pragma unroll
        for (int i = 0; i < 4; ++i)
#pragma unroll
            for (int j = 0; j < 4; ++j)
                acc[i][j] = __builtin_amdgcn_mfma_f32_16x16x32_bf16(a[i], b[j], acc[i][j], 0, 0, 0);
        __syncthreads();
    }
    // epilogue: + bias, squash over full 128 cols (pairs of waves share rows)
    float bpv[4];
#pragma unroll
    for (int j = 0; j < 4; ++j) bpv[j] = bp[n0 + cbase + j * 16 + lrow];
    float ns_[4][4];
#pragma unroll
    for (int i = 0; i < 4; ++i)
#pragma unroll
        for (int reg = 0; reg < 4; ++reg) {
            float ss = 0.f;
#pragma unroll
            for (int j = 0; j < 4; ++j) {
                float x = acc[i][j][reg] + bpv[j];
                acc[i][j][reg] = x;
                ss += x * x;
            }
            ss += __shfl_xor(ss, 1); ss += __shfl_xor(ss, 2);
            ss += __shfl_xor(ss, 4); ss += __shfl_xor(ss, 8);
            ns_[i][reg] = ss;
        }
    if (lrow == 0) {
#pragma unroll
        for (int i = 0; i < 4; ++i)
#pragma unroll
            for (int reg = 0; reg < 4; ++reg)
                sq[w & 1][rbase + i * 16 + koff * 4 + reg] = ns_[i][reg];
    }
    __syncthreads();
#pragma unroll
    for (int i = 0; i < 4; ++i)
#pragma unroll
        for (int reg = 0; reg < 4; ++reg) {
            int rl = rbase + i * 16 + koff * 4 + reg;
            float ns = sq[0][rl] + sq[1][rl];
            float factor = (ns / fmaxf(1.0f + ns, 1e-6f)) / (sqrtf(ns) + 1e-6f);
            size_t rowbase = ((size_t)(m0 + rl) * RR + r) * DP;
#pragma unroll
            for (int j = 0; j < 4; ++j)
                pose_out[rowbase + cbase + j * 16 + lrow] = acc[i][j][reg] * factor;
        }
}

// ---------------------------------------------------------------------------
// Kernel 3 (MFMA): votes u[b,r,:] = pose[b,r,:] @ w_caps[r]  (K=128, no K-loop)
// grid (B/128, R, 400/80). A: pose fp32->bf16 staged; B: wcT bf16 (ws).
// ---------------------------------------------------------------------------
__global__ __launch_bounds__(256) void votes_mfma(
    const float* __restrict__ pose, const unsigned short* __restrict__ wcT,
    float* __restrict__ u_out)
{
    __shared__ __align__(16) unsigned short As[128 * 152];  // [row][k<128] stride 152
    __shared__ __align__(16) unsigned short Bs[80 * 152];   // [col][k<128]
    int m0 = blockIdx.x * 128, r = blockIdx.y, n0 = blockIdx.z * 80;
    int t = threadIdx.x;
    int w = t >> 6, l = t & 63;
    int lrow = l & 15, koff = l >> 4;
    int rbase = w * 32;
    // stage A
#pragma unroll
    for (int q = 0; q < 16; ++q) {
        int s = t + 256 * q;
        int row = s >> 5, k4 = s & 31;
        float4 v = *(const float4*)(pose + ((size_t)(m0 + row) * RR + r) * DP + k4 * 4);
        *(uint2*)(As + row * 152 + k4 * 4) = make_uint2(pk_bf16(v.x, v.y), pk_bf16(v.z, v.w));
    }
    // stage B from wcT[r][n][d]
    const unsigned short* wr_ = wcT + (size_t)r * KH * DP;
#pragma unroll
    for (int q = 0; q < 5; ++q) {
        int s = t + 256 * q;
        int col = s >> 4, k8 = s & 15;
        uint4 v = *(const uint4*)(wr_ + (size_t)(n0 + col) * DP + k8 * 8);
        *(uint4*)(Bs + col * 152 + k8 * 8) = v;
    }
    __syncthreads();
    f32x4 acc[2][5];
#pragma unroll
    for (int i = 0; i < 2; ++i)
#pragma unroll
        for (int j = 0; j < 5; ++j) acc[i][j] = 0.0f;
#pragma unroll
    for (int ks = 0; ks < 4; ++ks) {
        bf16x8 a[2], b[5];
#pragma unroll
        for (int i = 0; i < 2; ++i)
            a[i] = *(const bf16x8*)(As + (rbase + i * 16 + lrow) * 152 + ks * 32 + koff * 8);
#pragma unroll
        for (int j = 0; j < 5; ++j)
            b[j] = *(const bf16x8*)(Bs + (j * 16 + lrow) * 152 + ks * 32 + koff * 8);
#pragma unroll
        for (int i = 0; i < 2; ++i)
#pragma unroll
            for (int j = 0; j < 5; ++j)
                acc[i][j] = __builtin_amdgcn_mfma_f32_16x16x32_bf16(a[i], b[j], acc[i][j], 0, 0, 0);
    }
#pragma unroll
    for (int i = 0; i < 2; ++i)
#pragma unroll
        for (int reg = 0; reg < 4; ++reg) {
            int row = m0 + rbase + i * 16 + koff * 4 + reg;
            size_t base = ((size_t)row * RR + r) * KH + n0;
#pragma unroll
            for (int j = 0; j < 5; ++j)
                u_out[base + j * 16 + lrow] = acc[i][j][reg];
        }
}

// ---------------------------------------------------------------------------
// Kernel 4: routing — one wave per batch row b. u[b] in LDS.
// ---------------------------------------------------------------------------
__global__ __launch_bounds__(64) void routing_kernel(
    const float* __restrict__ u_in, const float* __restrict__ act_in,
    const float* __restrict__ lncg, const float* __restrict__ lncb,
    const float* __restrict__ beta_u,
    float* __restrict__ q_out, float* __restrict__ cp_out,
    float* __restrict__ ca_out, float* __restrict__ rce_out,
    float* __restrict__ ce_out)
{
    __shared__ __align__(16) float U[RKH];
    __shared__ float Q[RK];
    __shared__ float CP[KH];
    __shared__ float AG[RK];
    __shared__ float A7[RR];
    int b = blockIdx.x, t = threadIdx.x;
    const float4* u4 = (const float4*)(u_in + (size_t)b * RKH);
    float4* U4 = (float4*)U;
    for (int p = t; p < RKH / 4; p += 64) U4[p] = u4[p];
    if (t < RR) A7[t] = act_in[(size_t)b * RR + t];
    for (int p = t; p < RK; p += 64) Q[p] = 1.0f / KK;
    __syncthreads();
    for (int it = 0; it < NITERS; ++it) {
        for (int p = t; p < KH; p += 64) {
            int k = p / DC;
            float s = 0.f;
#pragma unroll
            for (int r = 0; r < RR; ++r) s += Q[r * KK + k] * A7[r] * U[r * KH + p];
            CP[p] = s;
        }
        __syncthreads();
        if (t < KK) {
            float m = 0.f;
#pragma unroll
            for (int h = 0; h < DC; ++h) m += CP[t * DC + h];
            m *= (1.0f / DC);
            float v = 0.f;
#pragma unroll
            for (int h = 0; h < DC; ++h) { float d = CP[t * DC + h] - m; v += d * d; }
            v *= (1.0f / DC);
            float rstd = rsqrtf(v + 1e-5f);
#pragma unroll
            for (int h = 0; h < DC; ++h)
                CP[t * DC + h] = (CP[t * DC + h] - m) * rstd * lncg[h] + lncb[h];
        }
        __syncthreads();
        for (int p = t; p < RK; p += 64) {
            int r = p / KK, k = p % KK;
            float s = 0.f;
#pragma unroll
            for (int h = 0; h < DC; ++h) s += CP[k * DC + h] * U[r * KH + k * DC + h];
            AG[p] = s * 0.25f;
        }
        __syncthreads();
        if (t < RR) {
            float mx = -1e30f;
            for (int k = 0; k < KK; ++k) mx = fmaxf(mx, AG[t * KK + k]);
            float e[KK], sum = 0.f;
            for (int k = 0; k < KK; ++k) { e[k] = expf(AG[t * KK + k] - mx); sum += e[k]; }
            float inv = 1.0f / sum;
            for (int k = 0; k < KK; ++k) Q[t * KK + k] = e[k] * inv;
        }
        __syncthreads();
    }
    if (t < KK) {
        float s = 0.f;
#pragma unroll
        for (int r = 0; r < RR; ++r) s += Q[r * KK + t] * A7[r];
        ca_out[(size_t)b * KK + t] = 1.0f / (1.0f + expf(-(beta_u[t] + s)));
    }
    for (int p = t; p < RK; p += 64) q_out[(size_t)b * RK + p] = Q[p];
    for (int p = t; p < KH; p += 64) cp_out[(size_t)b * KH + p] = CP[p];
    float4* rce4 = (float4*)(rce_out + (size_t)b * RKH);
    float4* ce4  = (float4*)ce_out;
    for (int p4 = t; p4 < RKH / 4; p4 += 64) {
        int base = p4 * 4;
        int r  = base / KH;
        int k  = (base % KH) / DC;
        int h0 = base % DC;
        float qv = Q[r * KK + k];
        float4 uv = U4[p4];
        float4 rv = make_float4(qv * uv.x, qv * uv.y, qv * uv.z, qv * uv.w);
        rce4[p4] = rv;
        size_t ci = ((size_t)b * RKH + (size_t)k * HD + (size_t)r * DC + h0) >> 2;
        ce4[ci] = rv;
    }
}

// ---------------------------------------------------------------------------
// Kernel 5 (MFMA): head — LN(ce) @ W_h1 -> gelu -> dot W_h2. 128 rows/block.
// K=112 zero-padded to 128 in LDS; W1T bf16 from ws.
// ---------------------------------------------------------------------------
__global__ __launch_bounds__(256) void head_mfma(
    const float* __restrict__ ce, const float* __restrict__ g, const float* __restrict__ bb,
    const unsigned short* __restrict__ W1T, const float* __restrict__ b1,
    const float* __restrict__ W2, const float* __restrict__ b2,
    float* __restrict__ logits)
{
    __shared__ __align__(16) unsigned short As[128 * 152];   // bf16 LN'ed Y, k padded to 128
    __shared__ __align__(16) char pool[64 * 116 * 4];        // union: scr fp32 | Bs bf16
    __shared__ float gbuf[HD], bbuf[HD];
    float* scr = (float*)pool;                 // [64][116]
    unsigned short* Bs = (unsigned short*)pool; // [64 cols][152]
    unsigned* As32 = (unsigned*)As;
    unsigned* Bs32 = (unsigned*)Bs;
    int row0 = blockIdx.x * 128;
    int t = threadIdx.x;
    int w = t >> 6, l = t & 63;
    int lrow = l & 15, koff = l >> 4;
    if (t < HD) { gbuf[t] = g[t]; bbuf[t] = bb[t]; }
    for (int p = 0; p < 2; ++p) {
        for (int s = t; s < 64 * 28; s += 256) {
            int row = s / 28, q4 = s % 28;
            float4 v = *(const float4*)(ce + (size_t)(row0 + p * 64 + row) * HD + q4 * 4);
            *(float4*)(scr + row * 116 + q4 * 4) = v;
        }
        __syncthreads();
        {
            int tq = t & 3, row = t >> 2;   // row 0..63
            float s1 = 0.f, s2 = 0.f;
            const float* rp = scr + row * 116 + tq * 28;
            for (int q = 0; q < 28; ++q) { float v = rp[q]; s1 += v; s2 += v * v; }
            s1 += __shfl_xor(s1, 1); s2 += __shfl_xor(s2, 1);
            s1 += __shfl_xor(s1, 2); s2 += __shfl_xor(s2, 2);
            float mean = s1 * (1.0f / HD);
            float var  = s2 * (1.0f / HD) - mean * mean;
            float rstd = rsqrtf(var + 1e-5f);
            int grow = p * 64 + row;
            for (int j = 0; j < 14; ++j) {
                int k = tq * 28 + 2 * j;
                float a = (rp[2 * j]     - mean) * rstd * gbuf[k]     + bbuf[k];
                float bv = (rp[2 * j + 1] - mean) * rstd * gbuf[k + 1] + bbuf[k + 1];
                As32[grow * 76 + tq * 14 + j] = pk_bf16(a, bv);
            }
        }
        __syncthreads();
    }
    // zero pad k = 112..127 in As and Bs
    for (int s = t; s < 128 * 8; s += 256) { int row = s >> 3; As32[row * 76 + 56 + (s & 7)] = 0; }
    for (int s = t; s < 64 * 8;  s += 256) { int col = s >> 3; Bs32[col * 76 + 56 + (s & 7)] = 0; }
    int rbase = w * 32;
    float logitAcc[2][4];
#pragma unroll
    for (int i = 0; i < 2; ++i)
#pragma unroll
        for (int reg = 0; reg < 4; ++reg) logitAcc[i][reg] = 0.f;
    for (int nc = 0; nc < 7; ++nc) {
        __syncthreads();  // also covers pad-zero on first iteration
        for (int s = t; s < 64 * 14; s += 256) {
            int col = s / 14, k4 = s % 14;
            uint4 v = *(const uint4*)(W1T + (size_t)(nc * 64 + col) * HD + k4 * 8);
            *(uint4*)(Bs + col * 152 + k4 * 8) = v;
        }
        __syncthreads();
        f32x4 acc[2][4];
#pragma unroll
        for (int i = 0; i < 2; ++i)
#pragma unroll
            for (int j = 0; j < 4; ++j) acc[i][j] = 0.0f;
#pragma unroll
        for (int ks = 0; ks < 4; ++ks) {
            bf16x8 a[2], b[4];
#pragma unroll
            for (int i = 0; i < 2; ++i)
                a[i] = *(const bf16x8*)(As + (rbase + i * 16 + lrow) * 152 + ks * 32 + koff * 8);
#pragma unroll
            for (int j = 0; j < 4; ++j)
                b[j] = *(const bf16x8*)(Bs + (j * 16 + lrow) * 152 + ks * 32 + koff * 8);
#pragma unroll
            for (int i = 0; i < 2; ++i)
#pragma unroll
                for (int j = 0; j < 4; ++j)
                    acc[i][j] = __builtin_amdgcn_mfma_f32_16x16x32_bf16(a[i], b[j], acc[i][j], 0, 0, 0);
        }
        float b1v[4], w2v[4];
#pragma unroll
        for (int j = 0; j < 4; ++j) {
            b1v[j] = b1[nc * 64 + j * 16 + lrow];
            w2v[j] = W2[nc * 64 + j * 16 + lrow];
        }
#pragma unroll
        for (int i = 0; i < 2; ++i)
#pragma unroll
            for (int reg = 0; reg < 4; ++reg) {
                float sum = 0.f;
#pragma unroll
                for (int j = 0; j < 4; ++j) {
                    float x = acc[i][j][reg] + b1v[j];
                    sum += gelu_tanh(x) * w2v[j];
                }
                logitAcc[i][reg] += sum;
            }
    }
    // reduce over 16 col-lanes, store
#pragma unroll
    for (int i = 0; i < 2; ++i)
#pragma unroll
        for (int reg = 0; reg < 4; ++reg) {
            float v = logitAcc[i][reg];
            v += __shfl_xor(v, 1); v += __shfl_xor(v, 2);
            v += __shfl_xor(v, 4); v += __shfl_xor(v, 8);
            logitAcc[i][reg] = v;
        }
    if (lrow == 0) {
        float b2v = b2[0];
#pragma unroll
        for (int i = 0; i < 2; ++i)
#pragma unroll
            for (int reg = 0; reg < 4; ++reg)
                logits[row0 + rbase + i * 16 + koff * 4 + reg] = logitAcc[i][reg] + b2v;
    }
}

// ===========================================================================
// Fallback fp32 kernels (used only if ws_size is too small) — round-1 code.
// ===========================================================================
__global__ __launch_bounds__(256) void pose_kernel(
    const float* __restrict__ z, const float* __restrict__ Wp, const float* __restrict__ bp,
    float* __restrict__ pose_out)
{
    __shared__ __align__(16) float As[64 * 36];
    __shared__ __align__(16) float Bs[32 * 128];
    int m0 = blockIdx.x * 64;
    int r  = blockIdx.y;
    int n0 = r * DP;
    int t  = threadIdx.x;
    int rg = t >> 5;
    int cg = t & 31;
    float acc[8][4] = {};
    for (int kt = 0; kt < DIN; kt += 32) {
#pragma unroll
        for (int q = 0; q < 2; ++q) {
            int s = t * 2 + q;
            int row = s >> 3, k4 = s & 7;
            float4 v = *(const float4*)(z + (size_t)(m0 + row) * DIN + kt + k4 * 4);
            *(float4*)(As + row * 36 + k4 * 4) = v;
        }
#pragma unroll
        for (int q = 0; q < 4; ++q) {
            int s = t + 256 * q;
            int row = s >> 5, c4 = s & 31;
            float4 v = *(const float4*)(Wp + (size_t)(kt + row) * (RR * DP) + n0 + c4 * 4);
            *(float4*)(Bs + row * 128 + c4 * 4) = v;
        }
        __syncthreads();
#pragma unroll
        for (int kk = 0; kk < 32; ++kk) {
            float4 bv = *(const float4*)(Bs + kk * 128 + cg * 4);
#pragma unroll
            for (int j = 0; j < 8; ++j) {
                float a = As[(rg * 8 + j) * 36 + kk];
                acc[j][0] += a * bv.x; acc[j][1] += a * bv.y;
                acc[j][2] += a * bv.z; acc[j][3] += a * bv.w;
            }
        }
        __syncthreads();
    }
    float bi0 = bp[n0 + cg * 4], bi1 = bp[n0 + cg * 4 + 1];
    float bi2 = bp[n0 + cg * 4 + 2], bi3 = bp[n0 + cg * 4 + 3];
#pragma unroll
    for (int j = 0; j < 8; ++j) {
        float x0 = acc[j][0] + bi0, x1 = acc[j][1] + bi1;
        float x2 = acc[j][2] + bi2, x3 = acc[j][3] + bi3;
        float ns = x0 * x0 + x1 * x1 + x2 * x2 + x3 * x3;
        for (int off = 1; off < 32; off <<= 1) ns += __shfl_xor(ns, off);
        float factor = (ns / fmaxf(1.0f + ns, 1e-6f)) / (sqrtf(ns) + 1e-6f);
        int row = m0 + rg * 8 + j;
        float4 o = make_float4(x0 * factor, x1 * factor, x2 * factor, x3 * factor);
        *(float4*)(pose_out + ((size_t)row * RR + r) * DP + cg * 4) = o;
    }
}

__global__ __launch_bounds__(256) void votes_kernel(
    const float* __restrict__ pose, const float* __restrict__ wc,
    float* __restrict__ u_out)
{
    __shared__ float As[64 * 129];
    __shared__ __align__(16) float Bs[64 * 80];
    int m0 = blockIdx.x * 64;
    int r  = blockIdx.y;
    int n0 = blockIdx.z * 80;
    int t  = threadIdx.x;
    const size_t wbase = (size_t)r * DP * KH;
#pragma unroll
    for (int q = 0; q < 8; ++q) {
        int s = t + 256 * q;
        int row = s >> 5, d4 = s & 31;
        float4 v = *(const float4*)(pose + ((size_t)(m0 + row) * RR + r) * DP + d4 * 4);
        As[row * 129 + d4 * 4 + 0] = v.x;
        As[row * 129 + d4 * 4 + 1] = v.y;
        As[row * 129 + d4 * 4 + 2] = v.z;
        As[row * 129 + d4 * 4 + 3] = v.w;
    }
    int m4 = t >> 4, n5 = t & 15;
    float acc[4][5];
#pragma unroll
    for (int i = 0; i < 4; ++i)
#pragma unroll
        for (int j = 0; j < 5; ++j) acc[i][j] = 0.f;
    for (int kt = 0; kt < DP; kt += 64) {
        __syncthreads();
#pragma unroll
        for (int q = 0; q < 5; ++q) {
            int s = t + 256 * q;
            int d = s / 20, c4 = s % 20;
            float4 v = *(const float4*)(wc + wbase + (size_t)(kt + d) * KH + n0 + c4 * 4);
            *(float4*)(Bs + d * 80 + c4 * 4) = v;
        }
        __syncthreads();
#pragma unroll 4
        for (int dd = 0; dd < 64; ++dd) {
            int d = kt + dd;
            float b_[5];
#pragma unroll
            for (int j = 0; j < 5; ++j) b_[j] = Bs[dd * 80 + n5 * 5 + j];
#pragma unroll
            for (int i = 0; i < 4; ++i) {
                float a = As[(m4 * 4 + i) * 129 + d];
#pragma unroll
                for (int j = 0; j < 5; ++j) acc[i][j] += a * b_[j];
            }
        }
    }
#pragma unroll
    for (int i = 0; i < 4; ++i) {
        int row = m0 + m4 * 4 + i;
        size_t base = ((size_t)row * RR + r) * KH + n0 + n5 * 5;
#pragma unroll
        for (int j = 0; j < 5; ++j) u_out[base + j] = acc[i][j];
    }
}

__global__ __launch_bounds__(256) void head_kernel(
    const float* __restrict__ ce, const float* __restrict__ g, const float* __restrict__ bb,
    const float* __restrict__ W1, const float* __restrict__ b1,
    const float* __restrict__ W2, const float* __restrict__ b2,
    float* __restrict__ logits)
{
    __shared__ __align__(16) float Y[64 * HD];
    __shared__ float Wc[HD * 64];
    __shared__ float Lg[64];
    int row0 = blockIdx.x * 64;
    int t = threadIdx.x;
    for (int s = t; s < 64 * HD; s += 256) Y[s] = ce[(size_t)row0 * HD + s];
    __syncthreads();
    if (t < 64) {
        float m = 0.f;
        for (int i = 0; i < HD; ++i) m += Y[t * HD + i];
        m *= (1.0f / HD);
        float v = 0.f;
        for (int i = 0; i < HD; ++i) { float d = Y[t * HD + i] - m; v += d * d; }
        v *= (1.0f / HD);
        float rstd = rsqrtf(v + 1e-5f);
        for (int i = 0; i < HD; ++i) Y[t * HD + i] = (Y[t * HD + i] - m) * rstd * g[i] + bb[i];
    }
    int rg = t >> 4;
    int cg = t & 15;
    float accRow[4] = {0.f, 0.f, 0.f, 0.f};
    for (int c0 = 0; c0 < H4; c0 += 64) {
        __syncthreads();
        for (int s = t; s < HD * 64; s += 256) {
            int i = s >> 6, c = s & 63;
            Wc[i * 64 + c] = W1[(size_t)i * H4 + c0 + c];
        }
        __syncthreads();
        float b1v[4], w2v[4];
#pragma unroll
        for (int c = 0; c < 4; ++c) { b1v[c] = b1[c0 + cg * 4 + c]; w2v[c] = W2[c0 + cg * 4 + c]; }
        float s_[4][4];
#pragma unroll
        for (int rr = 0; rr < 4; ++rr)
#pragma unroll
            for (int c = 0; c < 4; ++c) s_[rr][c] = b1v[c];
        for (int i4 = 0; i4 < HD / 4; ++i4) {
            float4 y4[4];
#pragma unroll
            for (int rr = 0; rr < 4; ++rr)
                y4[rr] = *(const float4*)(Y + (rg * 4 + rr) * HD + i4 * 4);
#pragma unroll
            for (int is = 0; is < 4; ++is) {
                float w_[4];
#pragma unroll
                for (int c = 0; c < 4; ++c) w_[c] = Wc[(i4 * 4 + is) * 64 + cg * 4 + c];
#pragma unroll
                for (int rr = 0; rr < 4; ++rr) {
                    float yv = (is == 0) ? y4[rr].x : (is == 1) ? y4[rr].y : (is == 2) ? y4[rr].z : y4[rr].w;
#pragma unroll
                    for (int c = 0; c < 4; ++c) s_[rr][c] += yv * w_[c];
                }
            }
        }
#pragma unroll
        for (int rr = 0; rr < 4; ++rr) {
#pragma unroll
            for (int c = 0; c < 4; ++c) {
                float x = s_[rr][c];
                float ge = 0.5f * x * (1.0f + erff(x * 0.70710678118654752440f));
                accRow[rr] += ge * w2v[c];
            }
        }
    }
#pragma unroll
    for (int rr = 0; rr < 4; ++rr) {
        float v = accRow[rr];
        v += __shfl_xor(v, 1); v += __shfl_xor(v, 2);
        v += __shfl_xor(v, 4); v += __shfl_xor(v, 8);
        if (cg == 0) Lg[rg * 4 + rr] = v;
    }
    __syncthreads();
    if (t < 64) logits[row0 + t] = Lg[t] + b2[0];
}

// ---------------------------------------------------------------------------
extern "C" void kernel_launch(void* const* d_in, const int* in_sizes, int n_in,
                              void* d_out, int out_size, void* d_ws, size_t ws_size,
                              hipStream_t stream) {
    const float* z    = (const float*)d_in[0];
    const float* Wp   = (const float*)d_in[1];
    const float* bp   = (const float*)d_in[2];
    const float* lnag = (const float*)d_in[3];
    const float* lnab = (const float*)d_in[4];
    const float* Wa   = (const float*)d_in[5];
    const float* ba   = (const float*)d_in[6];
    const float* wc   = (const float*)d_in[7];
    const float* lncg = (const float*)d_in[8];
    const float* lncb = (const float*)d_in[9];
    const float* beta = (const float*)d_in[10];
    const float* lnhg = (const float*)d_in[11];
    const float* lnhb = (const float*)d_in[12];
    const float* W1   = (const float*)d_in[13];
    const float* b1   = (const float*)d_in[14];
    const float* W2   = (const float*)d_in[15];
    const float* b2   = (const float*)d_in[16];

    float* out = (float*)d_out;
    float* o_logits = out;
    float* o_ce   = o_logits + (size_t)BB * KK;
    float* o_cp   = o_ce   + (size_t)BB * KK * HD;
    float* o_ca   = o_cp   + (size_t)BB * KK * DC;
    float* o_q    = o_ca   + (size_t)BB * KK;
    float* o_pose = o_q    + (size_t)BB * RK;
    float* o_act  = o_pose + (size_t)BB * RR * DP;
    float* o_rce  = o_act  + (size_t)BB * RR;

    // workspace layout (bf16 transposed weights)
    const size_t WPT_ELE = (size_t)(RR * DP) * DIN;       // 896*2048
    const size_t W1T_ELE = (size_t)H4 * HD;               // 448*112
    const size_t WCT_ELE = (size_t)RR * KH * DP;          // 7*400*128
    const size_t WS_NEED = (WPT_ELE + W1T_ELE + WCT_ELE) * sizeof(unsigned short);
    unsigned short* WpT = (unsigned short*)d_ws;
    unsigned short* W1T = WpT + WPT_ELE;
    unsigned short* wcT = W1T + W1T_ELE;

    hipLaunchKernelGGL(act_kernel, dim3(BB), dim3(256), 0, stream,
                       z, lnag, lnab, Wa, ba, o_act);

    if (ws_size >= WS_NEED) {
        hipLaunchKernelGGL(transpose_cvt_kernel, dim3(DIN / 64, (RR * DP) / 64, 1), dim3(256), 0, stream,
                           Wp, WpT, DIN, RR * DP);
        hipLaunchKernelGGL(transpose_cvt_kernel, dim3(2, 7, 1), dim3(256), 0, stream,
                           W1, W1T, HD, H4);
        hipLaunchKernelGGL(transpose_cvt_kernel, dim3(2, 7, RR), dim3(256), 0, stream,
                           wc, wcT, DP, KH);
        hipLaunchKernelGGL(pose_mfma, dim3(BB / 128, RR), dim3(256), 0, stream,
                           z, WpT, bp, o_pose);
        hipLaunchKernelGGL(votes_mfma, dim3(BB / 128, RR, 5), dim3(256), 0, stream,
                           o_pose, wcT, o_rce);
        hipLaunchKernelGGL(routing_kernel, dim3(BB), dim3(64), 0, stream,
                           o_rce, o_act, lncg, lncb, beta, o_q, o_cp, o_ca, o_rce, o_ce);
        hipLaunchKernelGGL(head_mfma, dim3(BB * KK / 128), dim3(256), 0, stream,
                           o_ce, lnhg, lnhb, W1T, b1, W2, b2, o_logits);
    } else {
        hipLaunchKernelGGL(pose_kernel, dim3(BB / 64, RR), dim3(256), 0, stream,
                           z, Wp, bp, o_pose);
        hipLaunchKernelGGL(votes_kernel, dim3(BB / 64, RR, 5), dim3(256), 0, stream,
                           o_pose, wc, o_rce);
        hipLaunchKernelGGL(routing_kernel, dim3(BB), dim3(64), 0, stream,
                           o_rce, o_act, lncg, lncb, beta, o_q, o_cp, o_ca, o_rce, o_ce);
        hipLaunchKernelGGL(head_kernel, dim3(BB * KK / 64), dim3(256), 0, stream,
                           o_ce, lnhg, lnhb, W1, b1, W2, b2, o_logits);
    }
}